// Round 5
// baseline (365.560 us; speedup 1.0000x reference)
//
#include <hip/hip_runtime.h>

typedef __attribute__((ext_vector_type(8))) short bf16x8;
typedef __attribute__((ext_vector_type(4))) float f32x4;
typedef __attribute__((ext_vector_type(4))) unsigned short u16x4;
typedef __attribute__((ext_vector_type(8))) unsigned short u16x8;

__device__ __forceinline__ unsigned short bf16u(float x) {
    unsigned int u = __builtin_bit_cast(unsigned int, x);
    unsigned int r = (u + 0x7fffu + ((u >> 16) & 1u)) >> 16;
    return (unsigned short)r;
}
__device__ __forceinline__ void gll16(const void* g, void* l) {
    __builtin_amdgcn_global_load_lds((const __attribute__((address_space(1))) void*)g,
                                     (__attribute__((address_space(3))) void*)l, 16, 0, 0);
}

// ---------------------------------------------------------------------------
// One-shot zeroing: h_bf border, t_bf border ([8][4][66][66][64]), sum bufs.
// ---------------------------------------------------------------------------
__global__ __launch_bounds__(256) void zero_all(unsigned short* __restrict__ hbf,
                                                unsigned short* __restrict__ tbf,
                                                float* __restrict__ sums) {
    int i = blockIdx.x * 256 + threadIdx.x;
    u16x8 z8 = {0, 0, 0, 0, 0, 0, 0, 0};
    if (i < 16640) {
        int chv = i & 7, pb = i >> 3, pos = pb % 260, b = pb / 260;
        int y, x;
        if (pos < 66) { y = 0; x = pos; }
        else if (pos < 132) { y = 65; x = pos - 66; }
        else if (pos < 196) { y = pos - 131; x = 0; }
        else { y = pos - 195; x = 65; }
        *(u16x8*)&hbf[(((size_t)b * 66 + y) * 66 + x) * 64 + chv * 8] = z8;
    } else if (i < 83200) {
        int j = i - 16640;
        int chv = j & 7, pb = j >> 3;           // 8 chunks of 64ch
        int pos = pb % 260, bc = pb / 260;      // bc = b*4 + icb
        int y, x;
        if (pos < 66) { y = 0; x = pos; }
        else if (pos < 132) { y = 65; x = pos - 66; }
        else if (pos < 196) { y = pos - 131; x = 0; }
        else { y = pos - 195; x = 65; }
        *(u16x8*)&tbf[(((size_t)bc * 66 + y) * 66 + x) * 64 + chv * 8] = z8;
    } else {
        int k = i - 83200;  // < 2560
        f32x4 z4 = {0.f, 0.f, 0.f, 0.f};
        ((f32x4*)sums)[k] = z4;
    }
}

// ---------------------------------------------------------------------------
// All weight norms in one launch.
// ---------------------------------------------------------------------------
__global__ __launch_bounds__(256) void wn_all(
    const float* __restrict__ hv, const float* __restrict__ hg, float* __restrict__ hw,
    const float* __restrict__ tv, const float* __restrict__ tg, float* __restrict__ tw,
    const float* __restrict__ kv, const float* __restrict__ kg, float* __restrict__ kw,
    const float* __restrict__ b1v, const float* __restrict__ b1g, float* __restrict__ b1s,
    const float* __restrict__ b2v, const float* __restrict__ b2g, float* __restrict__ b2s) {
    int blk = blockIdx.x;
    const float *v, *g;
    float *outw = nullptr, *outs = nullptr;
    int len, row;
    if (blk < 64)        { v = hv;  g = hg;  outw = hw;  len = 27;   row = blk; }
    else if (blk < 76)   { v = tv;  g = tg;  outw = tw;  len = 576;  row = blk - 64; }
    else if (blk < 88)   { v = kv;  g = kg;  outw = kw;  len = 75;   row = blk - 76; }
    else if (blk < 2136) { v = b1v; g = b1g; outs = b1s; len = 576;  row = blk - 88; }
    else                 { v = b2v; g = b2g; outs = b2s; len = 2304; row = blk - 2136; }

    __shared__ float red[4];
    __shared__ float s_sc;
    const float* vr = v + (size_t)row * len;
    float ss = 0.f;
    for (int i = threadIdx.x; i < len; i += 256) { float a = vr[i]; ss += a * a; }
    for (int o = 32; o > 0; o >>= 1) ss += __shfl_down(ss, o);
    if ((threadIdx.x & 63) == 0) red[threadIdx.x >> 6] = ss;
    __syncthreads();
    if (threadIdx.x == 0) s_sc = g[row] / sqrtf(red[0] + red[1] + red[2] + red[3]);
    __syncthreads();
    float sc = s_sc;
    if (outs) {
        if (threadIdx.x == 0) outs[row] = sc;
    } else {
        float* orow = outw + (size_t)row * len;
        for (int i = threadIdx.x; i < len; i += 256) orow[i] = vr[i] * sc;
    }
}

// ---------------------------------------------------------------------------
// Coalesced per-sample weight combine + in-block routing softmax.
// Block = (GOC ocs, one sample). v rows loaded contiguously to LDS with
// wn-scale folded in; writes u16x8 fragment chunks [b][ot][kc][t][kg][mo][kj].
// ---------------------------------------------------------------------------
template <int IC, int GOC, int LGG>
__global__ __launch_bounds__(256) void combine_v2(
    const float* __restrict__ v, const float* __restrict__ scale,
    const float* __restrict__ msum, const float* __restrict__ mw,
    const float* __restrict__ mb, float* __restrict__ s_out,
    unsigned short* __restrict__ wq, int D, int OC) {
    constexpr int ROWF = IC * 9;
    constexpr int KCh = IC / 32;
    constexpr int TOTC = GOC * KCh * 9 * 4;
    __shared__ float lv[2 * GOC * ROWF];  // 4608 floats
    __shared__ float lg[8], sv8[8];
    int tid = threadIdx.x;
    int b = blockIdx.y, ocg = blockIdx.x * GOC;
    // routing logits (raw pixel sums -> mean)
    {
        int j = tid >> 5, l32 = tid & 31;
        float part = 0.f;
        for (int i = l32; i < IC; i += 32) part += msum[b * IC + i] * mw[j * IC + i];
        for (int m = 16; m > 0; m >>= 1) part += __shfl_xor(part, m);
        if (l32 == 0) lg[j] = part * (1.f / 4096.f) + mb[j];
    }
    // load v rows (scale folded)
    for (int i = tid; i < 2 * GOC * ROWF; i += 256) {
        int r = i / ROWF, jj = i - r * ROWF;
        int oc_r = (r / GOC) * OC + ocg + (r % GOC);
        lv[i] = v[(size_t)oc_r * ROWF + jj] * scale[oc_r];
    }
    __syncthreads();
    if (tid < 8) {
        int g = tid >> 2, c = tid & 3;
        float l0 = lg[c], l1 = lg[4 + c];
        float m = fmaxf(l0, l1);
        float e0 = __expf(l0 - m), e1 = __expf(l1 - m);
        float val = ((g == 0) ? e0 : e1) / (e0 + e1);
        sv8[tid] = val;
        if (blockIdx.x == 0) s_out[b * 8 + tid] = val;
    }
    __syncthreads();
    for (int ci = tid; ci < TOTC; ci += 256) {
        int ml = ci & (GOC - 1);
        int c = ci >> LGG;
        int kg = c & 3, c2 = c >> 2;
        int t = c2 % 9, kc = c2 / 9;
        int oc = ocg + ml;
        int cd = oc / D;
        float s0 = sv8[cd], s1 = sv8[4 + cd];
        const float* p0 = &lv[(size_t)ml * ROWF];
        const float* p1 = &lv[(size_t)(GOC + ml) * ROWF];
        u16x8 pk;
#pragma unroll
        for (int kj = 0; kj < 8; ++kj) {
            int ic9 = (kc * 32 + kg * 8 + kj) * 9 + t;
            pk[kj] = bf16u(s0 * p0[ic9] + s1 * p1[ic9]);
        }
        int ot = oc >> 6, mo = oc & 63;
        size_t w_off = ((((size_t)(b * (OC >> 6) + ot) * KCh + kc) * 9 + t) * 4 + kg) * 512 + mo * 8;
        *(u16x8*)&wq[w_off] = pk;
    }
}

// Static tail weight repack: [kc=2][t][kg][mo=16][kj], zeros for mo>=12
__global__ void tail_repack(const float* __restrict__ tw, unsigned short* __restrict__ wq) {
    int idx = blockIdx.x * 256 + threadIdx.x;  // 9216
    int kj = idx & 7;
    int tmp = idx >> 3;
    int mo = tmp % 16; tmp /= 16;
    int kg = tmp & 3; tmp >>= 2;
    int t = tmp % 9; tmp /= 9;
    int kc = tmp;
    int ic = kc * 32 + kg * 8 + kj;
    float val = (mo < 12) ? tw[((size_t)mo * 64 + ic) * 9 + t] : 0.f;
    wq[idx] = bf16u(val);
}

// ---------------------------------------------------------------------------
// MFMA implicit-GEMM 3x3 conv, 2-phase prefetch (double-buffered LDS, stage
// kc+1 issued BEFORE compute kc, one __syncthreads per kc).
// Input [8][IC/64][66][66][64] bf16; out_bf [8][OCR/64][66][66][64].
// ---------------------------------------------------------------------------
template <int IC, int OC, int MT, int WM, int WN, int NR,
          bool RELU, bool RES, bool WF32, bool WBF, int OCR, bool DYNB>
__global__ __launch_bounds__(256) void conv_mfma(
    const unsigned short* __restrict__ in_bf,
    const unsigned short* __restrict__ wq,
    const float* __restrict__ bias_raw, const float* __restrict__ s8, int lgD,
    const float* __restrict__ res, float* __restrict__ out,
    unsigned short* __restrict__ out_bf, float* __restrict__ msum, long wstride) {
    constexpr int KCH = IC / 32;
    constexpr int NRH = NR + 2;
    constexpr int NT = NR * 64;
    constexpr int NF = (NT / 16) / WN;
    constexpr int MW = MT / (16 * WM);
    constexpr int WELEM = 9 * 32 * MT;
    constexpr int SELEM = NRH * 66 * 32;
    constexpr int WCH = WELEM / 8;
    constexpr int SCH = SELEM / 8;
    constexpr int OCB = (OCR % 64 == 0) ? OCR / 64 : 1;

    __shared__ __align__(16) unsigned short S[2][SELEM];
    __shared__ __align__(16) unsigned short W[2][WELEM];
    __shared__ float MRED[WN][MT];

    const int b = blockIdx.z, ot = blockIdx.y;
    const int y0 = blockIdx.x * NR;
    const int tid = threadIdx.x;
    const int lane = tid & 63;
    const int wid = tid >> 6;
    const int wm = wid / WN, wn = wid % WN;
    const int l15 = lane & 15, lk = lane >> 4;
    const int wmo = wm * (MT / WM);
    const int wno = wn * (NT / WN);

    f32x4 acc[MW][NF];
#pragma unroll
    for (int mf = 0; mf < MW; ++mf)
#pragma unroll
        for (int nf = 0; nf < NF; ++nf)
#pragma unroll
            for (int q = 0; q < 4; ++q) acc[mf][nf][q] = 0.f;

    const unsigned short* inb = in_bf + (size_t)b * (IC / 64) * 4356 * 64;
    const unsigned short* wqb = wq + (size_t)b * wstride + (size_t)ot * (KCH * WELEM);

    auto STAGE = [&](int kc, int buf) {
        const unsigned short* wsrc = wqb + (size_t)kc * WELEM;
        for (int i = tid; i < WCH; i += 256)
            gll16(wsrc + i * 8, (char*)W[buf] + i * 16);
        const unsigned short* sb = inb + (size_t)(kc >> 1) * (4356 * 64) + (kc & 1) * 32;
        for (int i = tid; i < SCH; i += 256) {
            int Lz = i ^ ((i >> 3) & 7);
            int lk2 = Lz & 3, cr = Lz >> 2;
            int col = cr % 66, row = cr / 66;
            gll16(sb + ((size_t)(y0 + row) * 66 + col) * 64 + lk2 * 8,
                  (char*)S[buf] + i * 16);
        }
    };

    STAGE(0, 0);
    __syncthreads();
    for (int kc = 0; kc < KCH; ++kc) {
        if (kc + 1 < KCH) STAGE(kc + 1, (kc + 1) & 1);
        const unsigned short* Sb = S[kc & 1];
        const unsigned short* Wb = W[kc & 1];
#pragma unroll
        for (int t = 0; t < 9; ++t) {
            const int dy = t / 3, dx = t % 3;
            bf16x8 a[MW];
#pragma unroll
            for (int mf = 0; mf < MW; ++mf)
                a[mf] = *(const bf16x8*)&Wb[((t * 4 + lk) * MT + wmo + mf * 16 + l15) * 8];
#pragma unroll
            for (int nf = 0; nf < NF; ++nf) {
                int n = wno + nf * 16 + l15;
                int r = n >> 6, c = n & 63;
                int L = ((r + dy) * 66 + (c + dx)) * 4 + lk;
                int P = L ^ ((L >> 3) & 7);
                bf16x8 bv = *(const bf16x8*)((const char*)Sb + P * 16);
#pragma unroll
                for (int mf = 0; mf < MW; ++mf)
                    acc[mf][nf] = __builtin_amdgcn_mfma_f32_16x16x32_bf16(a[mf], bv, acc[mf][nf], 0, 0, 0);
            }
        }
        __syncthreads();
    }

    // epilogue: C/D map col=lane&15, row=(lane>>4)*4+q
    float msr[MW][4];
#pragma unroll
    for (int mf = 0; mf < MW; ++mf) {
        int ocb = ot * MT + wmo + mf * 16 + lk * 4;
        float bv[4];
#pragma unroll
        for (int q = 0; q < 4; ++q) {
            int oc = ocb + q;
            bv[q] = 0.f;
            if (oc < OCR) {
                if (DYNB) {
                    int c = oc >> lgD;
                    bv[q] = s8[b * 8 + c] * bias_raw[oc] + s8[b * 8 + 4 + c] * bias_raw[OCR + oc];
                } else {
                    bv[q] = bias_raw[oc];
                }
            }
            msr[mf][q] = 0.f;
        }
#pragma unroll
        for (int nf = 0; nf < NF; ++nf) {
            int n = wno + nf * 16 + l15;
            int y = y0 + (n >> 6), x = n & 63;
            float vv[4];
#pragma unroll
            for (int q = 0; q < 4; ++q) {
                int oc = ocb + q;
                float v = 0.f;
                if (oc < OCR) {
                    v = acc[mf][nf][q] + bv[q];
                    if (RELU) v = fmaxf(v, 0.f);
                    size_t o = (((size_t)b * OCR + oc) * 64 + y) * 64 + x;
                    if (RES) v += res[o];
                    if (WF32) out[o] = v;
                    msr[mf][q] += v;
                }
                vv[q] = v;
            }
            if (WBF) {
                u16x4 pk;
#pragma unroll
                for (int q = 0; q < 4; ++q) pk[q] = bf16u(vv[q]);
                if (ocb < OCR)
                    *(u16x4*)&out_bf[((((size_t)b * OCB + (ocb >> 6)) * 66 + y + 1) * 66 +
                                      (x + 1)) * 64 + (ocb & 63)] = pk;
            }
        }
    }
    if (msum) {
#pragma unroll
        for (int mf = 0; mf < MW; ++mf)
#pragma unroll
            for (int q = 0; q < 4; ++q) {
                float vq = msr[mf][q];
                vq += __shfl_xor(vq, 1);
                vq += __shfl_xor(vq, 2);
                vq += __shfl_xor(vq, 4);
                vq += __shfl_xor(vq, 8);
                if (l15 == 0) MRED[wn][wmo + mf * 16 + lk * 4 + q] = vq;
            }
        __syncthreads();
        if (tid < MT) {
            float tot = 0.f;
#pragma unroll
            for (int w2 = 0; w2 < WN; ++w2) tot += MRED[w2][tid];
            atomicAdd(&msum[b * OCR + ot * MT + tid], tot);
        }
    }
}

// ---------------------------------------------------------------------------
// Head conv 3->64 direct fp32; writes h (NCHW), h_bf (padded NHWC), hsum0.
// ---------------------------------------------------------------------------
__global__ __launch_bounds__(256) void head_conv(
    const float* __restrict__ in, const float* __restrict__ w,
    const float* __restrict__ bias, float* __restrict__ out,
    unsigned short* __restrict__ out_bf, float* __restrict__ hsum0) {
    constexpr int OCT = 16, IC = 3;
    __shared__ float s_in[34 * 34];
    __shared__ float s_w[OCT * 9];
    __shared__ float wred[4][OCT];
    int b = blockIdx.z;
    int ocBase = blockIdx.y * OCT;
    int ty0 = (blockIdx.x >> 1) * 32;
    int tx0 = (blockIdx.x & 1) * 32;
    int tid = threadIdx.x;
    int lane = tid & 63, wid = tid >> 6;
    int tx = tid & 15, ty = tid >> 4;

    float acc[OCT][4];
#pragma unroll
    for (int oc = 0; oc < OCT; ++oc)
#pragma unroll
        for (int p = 0; p < 4; ++p) acc[oc][p] = 0.f;

    const float* inb = in + (size_t)b * IC * 4096;
    for (int ic = 0; ic < IC; ++ic) {
        const float* src = inb + (size_t)ic * 4096;
        for (int i = tid; i < 34 * 34; i += 256) {
            int r = i / 34, cc = i % 34;
            int gy = ty0 + r - 1, gx = tx0 + cc - 1;
            float val = 0.f;
            if (gy >= 0 && gy < 64 && gx >= 0 && gx < 64) val = src[gy * 64 + gx] - 0.5f;
            s_in[i] = val;
        }
        for (int i = tid; i < OCT * 9; i += 256) {
            int oc = i / 9, t = i % 9;
            s_w[i] = w[((size_t)(ocBase + oc) * IC + ic) * 9 + t];
        }
        __syncthreads();
        float v[4][4];
#pragma unroll
        for (int r = 0; r < 4; ++r)
#pragma unroll
            for (int cc = 0; cc < 4; ++cc) v[r][cc] = s_in[(2 * ty + r) * 34 + (2 * tx + cc)];
#pragma unroll
        for (int oc = 0; oc < OCT; ++oc) {
#pragma unroll
            for (int ky = 0; ky < 3; ++ky)
#pragma unroll
                for (int kx = 0; kx < 3; ++kx) {
                    float wv = s_w[oc * 9 + ky * 3 + kx];
                    acc[oc][0] += wv * v[ky][kx];
                    acc[oc][1] += wv * v[ky][kx + 1];
                    acc[oc][2] += wv * v[ky + 1][kx];
                    acc[oc][3] += wv * v[ky + 1][kx + 1];
                }
        }
        __syncthreads();
    }
    int py = ty0 + 2 * ty, px = tx0 + 2 * tx;
#pragma unroll
    for (int oc = 0; oc < OCT; ++oc) {
        int og = ocBase + oc;
        float bv = bias[og];
        float osum = 0.f;
#pragma unroll
        for (int p = 0; p < 4; ++p) {
            int dy = p >> 1, dx = p & 1;
            float val = acc[oc][p] + bv;
            osum += val;
            out[(((size_t)b * 64 + og) * 64 + py + dy) * 64 + px + dx] = val;
            out_bf[(((size_t)b * 66 + py + dy + 1) * 66 + (px + dx + 1)) * 64 + og] = bf16u(val);
        }
        for (int m = 1; m < 64; m <<= 1) osum += __shfl_xor(osum, m);
        if (lane == 0) wred[wid][oc] = osum;
    }
    __syncthreads();
    if (tid < OCT)
        atomicAdd(&hsum0[b * 64 + ocBase + tid],
                  wred[0][tid] + wred[1][tid] + wred[2][tid] + wred[3][tid]);
}

// ---------------------------------------------------------------------------
// Pixel shuffle + fused 5x5 skip conv + IMAGE_MEAN. out [8,3,128,128]
// ---------------------------------------------------------------------------
__global__ __launch_bounds__(256) void shuffle_skip(
    const float* __restrict__ body, const float* __restrict__ x,
    const float* __restrict__ skw, const float* __restrict__ skb,
    float* __restrict__ out) {
    __shared__ float w[900];
    __shared__ float bb[12];
    int tid = threadIdx.x;
    for (int i = tid; i < 900; i += 256) w[i] = skw[i];
    if (tid < 12) bb[tid] = skb[tid];
    __syncthreads();
    int idx = blockIdx.x * 256 + tid;
    int ox = idx & 127;
    int oy = (idx >> 7) & 127;
    int v = idx >> 14;
    int c = v % 3;
    int b = v / 3;
    int rx = ox & 1, ry = oy & 1;
    int xx = ox >> 1, yy = oy >> 1;
    int ch = c * 4 + ry * 2 + rx;
    float acc = bb[ch];
    for (int ic = 0; ic < 3; ++ic)
        for (int ky = 0; ky < 5; ++ky) {
            int gy = yy + ky - 2;
            if (gy < 0 || gy >= 64) continue;
            for (int kx = 0; kx < 5; ++kx) {
                int gx = xx + kx - 2;
                if (gx < 0 || gx >= 64) continue;
                acc += w[((ch * 3 + ic) * 5 + ky) * 5 + kx] *
                       (x[((size_t)(b * 3 + ic) * 64 + gy) * 64 + gx] - 0.5f);
            }
        }
    size_t src = (((size_t)b * 12 + ch) * 64 + yy) * 64 + xx;
    out[idx] = body[src] + acc + 0.5f;
}

// ---------------------------------------------------------------------------
extern "C" void kernel_launch(void* const* d_in, const int* in_sizes, int n_in,
                              void* d_out, int out_size, void* d_ws, size_t ws_size,
                              hipStream_t stream) {
    const float* x      = (const float*)d_in[0];
    const float* head_v = (const float*)d_in[1];
    const float* head_g = (const float*)d_in[2];
    const float* head_b = (const float*)d_in[3];
    const float* b1_v   = (const float*)d_in[4];
    const float* b1_g   = (const float*)d_in[5];
    const float* b1_b   = (const float*)d_in[6];
    const float* b1_mw  = (const float*)d_in[7];
    const float* b1_mb  = (const float*)d_in[8];
    const float* b2_v   = (const float*)d_in[9];
    const float* b2_g   = (const float*)d_in[10];
    const float* b2_b   = (const float*)d_in[11];
    const float* b2_mw  = (const float*)d_in[12];
    const float* b2_mb  = (const float*)d_in[13];
    const float* tail_v = (const float*)d_in[14];
    const float* tail_g = (const float*)d_in[15];
    const float* tail_b = (const float*)d_in[16];
    const float* skip_v = (const float*)d_in[17];
    const float* skip_g = (const float*)d_in[18];
    const float* skip_b = (const float*)d_in[19];

    float* ws = (float*)d_ws;
    size_t off = 0;
    auto alloc = [&](size_t n) { float* p = ws + off; off += (n + 3) & ~(size_t)3; return p; };
    float* head_w = alloc(64 * 27);
    float* tail_w = alloc(12 * 576);
    float* skip_w = alloc(12 * 75);
    float* b1_sc  = alloc(2048);
    float* b2_sc  = alloc(512);
    float* h      = alloc((size_t)8 * 64 * 4096);
    float* sums   = alloc(10240);   // hsum[4] @ l*512 ; tsum[4] @ 2048 + l*2048
    float* sbuf   = alloc(64);
    float* body   = alloc((size_t)8 * 12 * 4096);
    unsigned short* wq1  = (unsigned short*)alloc((size_t)8 * 256 * 576 / 2);
    unsigned short* wq2  = (unsigned short*)alloc((size_t)8 * 64 * 2304 / 2);
    unsigned short* wqt  = (unsigned short*)alloc(9216 / 2);
    unsigned short* h_bf = (unsigned short*)alloc((size_t)8 * 66 * 66 * 64 / 2);
    unsigned short* t_bf = (unsigned short*)alloc((size_t)8 * 4 * 66 * 66 * 64 / 2);
    (void)ws_size; (void)in_sizes; (void)n_in; (void)out_size;

    auto hsum = [&](int l) { return sums + l * 512; };
    auto tsum = [&](int l) { return sums + 2048 + l * 2048; };

    zero_all<<<335, 256, 0, stream>>>(h_bf, t_bf, sums);
    wn_all<<<2648, 256, 0, stream>>>(head_v, head_g, head_w, tail_v, tail_g, tail_w,
                                     skip_v, skip_g, skip_w, b1_v, b1_g, b1_sc,
                                     b2_v, b2_g, b2_sc);
    head_conv<<<dim3(4, 4, 8), 256, 0, stream>>>(x, head_w, head_b, h, h_bf, hsum(0));
    tail_repack<<<36, 256, 0, stream>>>(tail_w, wqt);

    for (int l = 0; l < 4; ++l) {
        // dyn conv 1: 64 -> 256, relu
        combine_v2<64, 4, 2><<<dim3(64, 8), 256, 0, stream>>>(
            b1_v + (size_t)l * 512 * 576, b1_sc + (size_t)l * 512, hsum(l),
            b1_mw + (size_t)l * 8 * 64, b1_mb + l * 8, sbuf, wq1, 64, 256);
        conv_mfma<64, 256, 64, 1, 4, 4, true, false, false, true, 256, true>
            <<<dim3(16, 4, 8), 256, 0, stream>>>(h_bf, wq1, b1_b + (size_t)l * 512, sbuf, 6,
                                                 nullptr, nullptr, t_bf, tsum(l), 147456);
        // dyn conv 2: 256 -> 64, +residual h
        combine_v2<256, 2, 1><<<dim3(32, 8), 256, 0, stream>>>(
            b2_v + (size_t)l * 128 * 2304, b2_sc + (size_t)l * 128, tsum(l),
            b2_mw + (size_t)l * 8 * 256, b2_mb + l * 8, sbuf, wq2, 16, 64);
        conv_mfma<256, 64, 64, 2, 2, 2, false, true, true, true, 64, true>
            <<<dim3(32, 1, 8), 256, 0, stream>>>(t_bf, wq2, b2_b + (size_t)l * 128, sbuf, 4,
                                                 h, h, h_bf, (l < 3) ? hsum(l + 1) : nullptr,
                                                 147456);
    }

    // tail: 64 -> 12 via MFMA (padded to 16)
    conv_mfma<64, 16, 16, 1, 4, 4, false, false, true, false, 12, false>
        <<<dim3(16, 1, 8), 256, 0, stream>>>(h_bf, wqt, tail_b, nullptr, 0,
                                             nullptr, body, nullptr, nullptr, 0);
    // pixel shuffle + fused skip conv
    shuffle_skip<<<1536, 256, 0, stream>>>(body, x, skip_w, skip_b, (float*)d_out);
}

// Round 6
// 356.400 us; speedup vs baseline: 1.0257x; 1.0257x over previous
//
#include <hip/hip_runtime.h>

typedef __attribute__((ext_vector_type(8))) short bf16x8;
typedef __attribute__((ext_vector_type(4))) float f32x4;
typedef __attribute__((ext_vector_type(4))) unsigned short u16x4;
typedef __attribute__((ext_vector_type(8))) unsigned short u16x8;

__device__ __forceinline__ unsigned short bf16u(float x) {
    unsigned int u = __builtin_bit_cast(unsigned int, x);
    unsigned int r = (u + 0x7fffu + ((u >> 16) & 1u)) >> 16;
    return (unsigned short)r;
}
__device__ __forceinline__ void gll16(const void* g, void* l) {
    __builtin_amdgcn_global_load_lds((const __attribute__((address_space(1))) void*)g,
                                     (__attribute__((address_space(3))) void*)l, 16, 0, 0);
}

// ---------------------------------------------------------------------------
// One-shot zeroing: h_bf border, t_bf border ([8][4][66][66][64]), sum bufs.
// ---------------------------------------------------------------------------
__global__ __launch_bounds__(256) void zero_all(unsigned short* __restrict__ hbf,
                                                unsigned short* __restrict__ tbf,
                                                float* __restrict__ sums) {
    int i = blockIdx.x * 256 + threadIdx.x;
    u16x8 z8 = {0, 0, 0, 0, 0, 0, 0, 0};
    if (i < 16640) {
        int chv = i & 7, pb = i >> 3, pos = pb % 260, b = pb / 260;
        int y, x;
        if (pos < 66) { y = 0; x = pos; }
        else if (pos < 132) { y = 65; x = pos - 66; }
        else if (pos < 196) { y = pos - 131; x = 0; }
        else { y = pos - 195; x = 65; }
        *(u16x8*)&hbf[(((size_t)b * 66 + y) * 66 + x) * 64 + chv * 8] = z8;
    } else if (i < 83200) {
        int j = i - 16640;
        int chv = j & 7, pb = j >> 3;           // 8 chunks of 64ch
        int pos = pb % 260, bc = pb / 260;      // bc = b*4 + icb
        int y, x;
        if (pos < 66) { y = 0; x = pos; }
        else if (pos < 132) { y = 65; x = pos - 66; }
        else if (pos < 196) { y = pos - 131; x = 0; }
        else { y = pos - 195; x = 65; }
        *(u16x8*)&tbf[(((size_t)bc * 66 + y) * 66 + x) * 64 + chv * 8] = z8;
    } else {
        int k = i - 83200;  // < 2560
        f32x4 z4 = {0.f, 0.f, 0.f, 0.f};
        ((f32x4*)sums)[k] = z4;
    }
}

// ---------------------------------------------------------------------------
// All weight norms in one launch.
// ---------------------------------------------------------------------------
__global__ __launch_bounds__(256) void wn_all(
    const float* __restrict__ hv, const float* __restrict__ hg, float* __restrict__ hw,
    const float* __restrict__ tv, const float* __restrict__ tg, float* __restrict__ tw,
    const float* __restrict__ kv, const float* __restrict__ kg, float* __restrict__ kw,
    const float* __restrict__ b1v, const float* __restrict__ b1g, float* __restrict__ b1s,
    const float* __restrict__ b2v, const float* __restrict__ b2g, float* __restrict__ b2s) {
    int blk = blockIdx.x;
    const float *v, *g;
    float *outw = nullptr, *outs = nullptr;
    int len, row;
    if (blk < 64)        { v = hv;  g = hg;  outw = hw;  len = 27;   row = blk; }
    else if (blk < 76)   { v = tv;  g = tg;  outw = tw;  len = 576;  row = blk - 64; }
    else if (blk < 88)   { v = kv;  g = kg;  outw = kw;  len = 75;   row = blk - 76; }
    else if (blk < 2136) { v = b1v; g = b1g; outs = b1s; len = 576;  row = blk - 88; }
    else                 { v = b2v; g = b2g; outs = b2s; len = 2304; row = blk - 2136; }

    __shared__ float red[4];
    __shared__ float s_sc;
    const float* vr = v + (size_t)row * len;
    float ss = 0.f;
    for (int i = threadIdx.x; i < len; i += 256) { float a = vr[i]; ss += a * a; }
    for (int o = 32; o > 0; o >>= 1) ss += __shfl_down(ss, o);
    if ((threadIdx.x & 63) == 0) red[threadIdx.x >> 6] = ss;
    __syncthreads();
    if (threadIdx.x == 0) s_sc = g[row] / sqrtf(red[0] + red[1] + red[2] + red[3]);
    __syncthreads();
    float sc = s_sc;
    if (outs) {
        if (threadIdx.x == 0) outs[row] = sc;
    } else {
        float* orow = outw + (size_t)row * len;
        for (int i = threadIdx.x; i < len; i += 256) orow[i] = vr[i] * sc;
    }
}

// ---------------------------------------------------------------------------
// Coalesced per-sample weight combine + in-block routing softmax.
// Writes u16x8 fragment chunks [b][ot][kc][t][kg][mo(64)][kj(8)].
// ---------------------------------------------------------------------------
template <int IC, int GOC, int LGG>
__global__ __launch_bounds__(256) void combine_v2(
    const float* __restrict__ v, const float* __restrict__ scale,
    const float* __restrict__ msum, const float* __restrict__ mw,
    const float* __restrict__ mb, float* __restrict__ s_out,
    unsigned short* __restrict__ wq, int D, int OC) {
    constexpr int ROWF = IC * 9;
    constexpr int KCh = IC / 32;
    constexpr int TOTC = GOC * KCh * 9 * 4;
    __shared__ float lv[2 * GOC * ROWF];  // 4608 floats
    __shared__ float lg[8], sv8[8];
    int tid = threadIdx.x;
    int b = blockIdx.y, ocg = blockIdx.x * GOC;
    // routing logits (raw pixel sums -> mean)
    {
        int j = tid >> 5, l32 = tid & 31;
        float part = 0.f;
        for (int i = l32; i < IC; i += 32) part += msum[b * IC + i] * mw[j * IC + i];
        for (int m = 16; m > 0; m >>= 1) part += __shfl_xor(part, m);
        if (l32 == 0) lg[j] = part * (1.f / 4096.f) + mb[j];
    }
    // load v rows (scale folded)
    for (int i = tid; i < 2 * GOC * ROWF; i += 256) {
        int r = i / ROWF, jj = i - r * ROWF;
        int oc_r = (r / GOC) * OC + ocg + (r % GOC);
        lv[i] = v[(size_t)oc_r * ROWF + jj] * scale[oc_r];
    }
    __syncthreads();
    if (tid < 8) {
        int g = tid >> 2, c = tid & 3;
        float l0 = lg[c], l1 = lg[4 + c];
        float m = fmaxf(l0, l1);
        float e0 = __expf(l0 - m), e1 = __expf(l1 - m);
        float val = ((g == 0) ? e0 : e1) / (e0 + e1);
        sv8[tid] = val;
        if (blockIdx.x == 0) s_out[b * 8 + tid] = val;
    }
    __syncthreads();
    for (int ci = tid; ci < TOTC; ci += 256) {
        int ml = ci & (GOC - 1);
        int c = ci >> LGG;
        int kg = c & 3, c2 = c >> 2;
        int t = c2 % 9, kc = c2 / 9;
        int oc = ocg + ml;
        int cd = oc / D;
        float s0 = sv8[cd], s1 = sv8[4 + cd];
        const float* p0 = &lv[(size_t)ml * ROWF];
        const float* p1 = &lv[(size_t)(GOC + ml) * ROWF];
        u16x8 pk;
#pragma unroll
        for (int kj = 0; kj < 8; ++kj) {
            int ic9 = (kc * 32 + kg * 8 + kj) * 9 + t;
            pk[kj] = bf16u(s0 * p0[ic9] + s1 * p1[ic9]);
        }
        int ot = oc >> 6, mo = oc & 63;
        size_t w_off = ((((size_t)(b * (OC >> 6) + ot) * KCh + kc) * 9 + t) * 4 + kg) * 512 + mo * 8;
        *(u16x8*)&wq[w_off] = pk;
    }
}

// Static tail weight repack: [kc=2][t][kg][mo=16][kj], zeros for mo>=12
__global__ void tail_repack(const float* __restrict__ tw, unsigned short* __restrict__ wq) {
    int idx = blockIdx.x * 256 + threadIdx.x;  // 9216
    int kj = idx & 7;
    int tmp = idx >> 3;
    int mo = tmp % 16; tmp /= 16;
    int kg = tmp & 3; tmp >>= 2;
    int t = tmp % 9; tmp /= 9;
    int kc = tmp;
    int ic = kc * 32 + kg * 8 + kj;
    float val = (mo < 12) ? tw[((size_t)mo * 64 + ic) * 9 + t] : 0.f;
    wq[idx] = bf16u(val);
}

// ---------------------------------------------------------------------------
// MFMA implicit-GEMM 3x3 conv. S-tile double-buffered in LDS (2-phase
// prefetch); A-fragments loaded per-tap from global into registers
// (fragment-ordered wq, L1/L2 served). Block = WM x WN waves.
// ---------------------------------------------------------------------------
template <int IC, int OC, int MT, int WM, int WN, int NR,
          bool RELU, bool RES, bool WF32, bool WBF, int OCR, bool DYNB>
__global__ __launch_bounds__(WM * WN * 64, ((WM * WN * 64) == 256) ? 3 : 2)
void conv_mfma(
    const unsigned short* __restrict__ in_bf,
    const unsigned short* __restrict__ wq,
    const float* __restrict__ bias_raw, const float* __restrict__ s8, int lgD,
    const float* __restrict__ res, float* __restrict__ out,
    unsigned short* __restrict__ out_bf, float* __restrict__ msum, long wstride) {
    constexpr int THREADS = WM * WN * 64;
    constexpr int KCH = IC / 32;
    constexpr int NRH = NR + 2;
    constexpr int NT = NR * 64;
    constexpr int NF = (NT / 16) / WN;
    constexpr int MW = MT / (16 * WM);
    constexpr int WELEM = 9 * 32 * MT;   // bf16 elems per kc chunk
    constexpr int SELEM = NRH * 66 * 32;
    constexpr int SCH = SELEM / 8;
    constexpr int OCB = (OCR % 64 == 0) ? OCR / 64 : 1;

    __shared__ __align__(16) unsigned short S[2][SELEM];
    __shared__ float MRED[WN][MT];

    const int b = blockIdx.z, ot = blockIdx.y;
    const int y0 = blockIdx.x * NR;
    const int tid = threadIdx.x;
    const int lane = tid & 63;
    const int wid = tid >> 6;
    const int wm = wid / WN, wn = wid % WN;
    const int l15 = lane & 15, lk = lane >> 4;
    const int wmo = wm * (MT / WM);
    const int wno = wn * (NT / WN);

    f32x4 acc[MW][NF];
#pragma unroll
    for (int mf = 0; mf < MW; ++mf)
#pragma unroll
        for (int nf = 0; nf < NF; ++nf)
#pragma unroll
            for (int q = 0; q < 4; ++q) acc[mf][nf][q] = 0.f;

    const unsigned short* inb = in_bf + (size_t)b * (IC / 64) * 4356 * 64;
    const unsigned short* wqb = wq + (size_t)b * wstride + (size_t)ot * (KCH * WELEM);
    // per-lane A base: elem offset = lk*(MT*8) + (wmo+l15)*8; frag(kc,t,mf) adds
    // (kc*9+t)*(4*MT*8) + mf*128
    const unsigned short* wqa = wqb + (size_t)lk * (MT * 8) + (size_t)(wmo + l15) * 8;

    auto STAGE_S = [&](int kc, int buf) {
        const unsigned short* sb = inb + (size_t)(kc >> 1) * (4356 * 64) + (kc & 1) * 32;
        for (int i = tid; i < SCH; i += THREADS) {
            int Lz = i ^ ((i >> 3) & 7);
            int lk2 = Lz & 3, cr = Lz >> 2;
            int col = cr % 66, row = cr / 66;
            gll16(sb + ((size_t)(y0 + row) * 66 + col) * 64 + lk2 * 8,
                  (char*)S[buf] + i * 16);
        }
    };

    STAGE_S(0, 0);
    __syncthreads();
    for (int kc = 0; kc < KCH; ++kc) {
        if (kc + 1 < KCH) STAGE_S(kc + 1, (kc + 1) & 1);
        const unsigned short* Sb = S[kc & 1];
        const unsigned short* wk = wqa + (size_t)kc * 9 * (4 * MT * 8);
        bf16x8 aN[MW];
#pragma unroll
        for (int mf = 0; mf < MW; ++mf)
            aN[mf] = *(const bf16x8*)(wk + mf * 128);
#pragma unroll
        for (int t = 0; t < 9; ++t) {
            const int dy = t / 3, dx = t % 3;
            bf16x8 aC[MW];
#pragma unroll
            for (int mf = 0; mf < MW; ++mf) aC[mf] = aN[mf];
            if (t < 8) {
#pragma unroll
                for (int mf = 0; mf < MW; ++mf)
                    aN[mf] = *(const bf16x8*)(wk + (t + 1) * (4 * MT * 8) + mf * 128);
            }
#pragma unroll
            for (int nf = 0; nf < NF; ++nf) {
                int n = wno + nf * 16 + l15;
                int r = n >> 6, c = n & 63;
                int L = ((r + dy) * 66 + (c + dx)) * 4 + lk;
                int P = L ^ ((L >> 3) & 7);
                bf16x8 bv = *(const bf16x8*)((const char*)Sb + P * 16);
#pragma unroll
                for (int mf = 0; mf < MW; ++mf)
                    acc[mf][nf] = __builtin_amdgcn_mfma_f32_16x16x32_bf16(aC[mf], bv, acc[mf][nf], 0, 0, 0);
            }
        }
        __syncthreads();
    }

    // epilogue: C/D map col=lane&15, row=(lane>>4)*4+q
    float msr[MW][4];
#pragma unroll
    for (int mf = 0; mf < MW; ++mf) {
        int ocb = ot * MT + wmo + mf * 16 + lk * 4;
        float bv[4];
#pragma unroll
        for (int q = 0; q < 4; ++q) {
            int oc = ocb + q;
            bv[q] = 0.f;
            if (oc < OCR) {
                if (DYNB) {
                    int c = oc >> lgD;
                    bv[q] = s8[b * 8 + c] * bias_raw[oc] + s8[b * 8 + 4 + c] * bias_raw[OCR + oc];
                } else {
                    bv[q] = bias_raw[oc];
                }
            }
            msr[mf][q] = 0.f;
        }
#pragma unroll
        for (int nf = 0; nf < NF; ++nf) {
            int n = wno + nf * 16 + l15;
            int y = y0 + (n >> 6), x = n & 63;
            float vv[4];
#pragma unroll
            for (int q = 0; q < 4; ++q) {
                int oc = ocb + q;
                float v = 0.f;
                if (oc < OCR) {
                    v = acc[mf][nf][q] + bv[q];
                    if (RELU) v = fmaxf(v, 0.f);
                    size_t o = (((size_t)b * OCR + oc) * 64 + y) * 64 + x;
                    if (RES) v += res[o];
                    if (WF32) out[o] = v;
                    msr[mf][q] += v;
                }
                vv[q] = v;
            }
            if (WBF) {
                u16x4 pk;
#pragma unroll
                for (int q = 0; q < 4; ++q) pk[q] = bf16u(vv[q]);
                if (ocb < OCR)
                    *(u16x4*)&out_bf[((((size_t)b * OCB + (ocb >> 6)) * 66 + y + 1) * 66 +
                                      (x + 1)) * 64 + (ocb & 63)] = pk;
            }
        }
    }
    if (msum) {
#pragma unroll
        for (int mf = 0; mf < MW; ++mf)
#pragma unroll
            for (int q = 0; q < 4; ++q) {
                float vq = msr[mf][q];
                vq += __shfl_xor(vq, 1);
                vq += __shfl_xor(vq, 2);
                vq += __shfl_xor(vq, 4);
                vq += __shfl_xor(vq, 8);
                if (l15 == 0) MRED[wn][wmo + mf * 16 + lk * 4 + q] = vq;
            }
        __syncthreads();
        if (tid < MT) {
            float tot = 0.f;
#pragma unroll
            for (int w2 = 0; w2 < WN; ++w2) tot += MRED[w2][tid];
            atomicAdd(&msum[b * OCR + ot * MT + tid], tot);
        }
    }
}

// ---------------------------------------------------------------------------
// Head conv 3->64 direct fp32; writes h (NCHW), h_bf (padded NHWC), hsum0.
// ---------------------------------------------------------------------------
__global__ __launch_bounds__(256) void head_conv(
    const float* __restrict__ in, const float* __restrict__ w,
    const float* __restrict__ bias, float* __restrict__ out,
    unsigned short* __restrict__ out_bf, float* __restrict__ hsum0) {
    constexpr int OCT = 16, IC = 3;
    __shared__ float s_in[34 * 34];
    __shared__ float s_w[OCT * 9];
    __shared__ float wred[4][OCT];
    int b = blockIdx.z;
    int ocBase = blockIdx.y * OCT;
    int ty0 = (blockIdx.x >> 1) * 32;
    int tx0 = (blockIdx.x & 1) * 32;
    int tid = threadIdx.x;
    int lane = tid & 63, wid = tid >> 6;
    int tx = tid & 15, ty = tid >> 4;

    float acc[OCT][4];
#pragma unroll
    for (int oc = 0; oc < OCT; ++oc)
#pragma unroll
        for (int p = 0; p < 4; ++p) acc[oc][p] = 0.f;

    const float* inb = in + (size_t)b * IC * 4096;
    for (int ic = 0; ic < IC; ++ic) {
        const float* src = inb + (size_t)ic * 4096;
        for (int i = tid; i < 34 * 34; i += 256) {
            int r = i / 34, cc = i % 34;
            int gy = ty0 + r - 1, gx = tx0 + cc - 1;
            float val = 0.f;
            if (gy >= 0 && gy < 64 && gx >= 0 && gx < 64) val = src[gy * 64 + gx] - 0.5f;
            s_in[i] = val;
        }
        for (int i = tid; i < OCT * 9; i += 256) {
            int oc = i / 9, t = i % 9;
            s_w[i] = w[((size_t)(ocBase + oc) * IC + ic) * 9 + t];
        }
        __syncthreads();
        float v[4][4];
#pragma unroll
        for (int r = 0; r < 4; ++r)
#pragma unroll
            for (int cc = 0; cc < 4; ++cc) v[r][cc] = s_in[(2 * ty + r) * 34 + (2 * tx + cc)];
#pragma unroll
        for (int oc = 0; oc < OCT; ++oc) {
#pragma unroll
            for (int ky = 0; ky < 3; ++ky)
#pragma unroll
                for (int kx = 0; kx < 3; ++kx) {
                    float wv = s_w[oc * 9 + ky * 3 + kx];
                    acc[oc][0] += wv * v[ky][kx];
                    acc[oc][1] += wv * v[ky][kx + 1];
                    acc[oc][2] += wv * v[ky + 1][kx];
                    acc[oc][3] += wv * v[ky + 1][kx + 1];
                }
        }
        __syncthreads();
    }
    int py = ty0 + 2 * ty, px = tx0 + 2 * tx;
#pragma unroll
    for (int oc = 0; oc < OCT; ++oc) {
        int og = ocBase + oc;
        float bv = bias[og];
        float osum = 0.f;
#pragma unroll
        for (int p = 0; p < 4; ++p) {
            int dy = p >> 1, dx = p & 1;
            float val = acc[oc][p] + bv;
            osum += val;
            out[(((size_t)b * 64 + og) * 64 + py + dy) * 64 + px + dx] = val;
            out_bf[(((size_t)b * 66 + py + dy + 1) * 66 + (px + dx + 1)) * 64 + og] = bf16u(val);
        }
        for (int m = 1; m < 64; m <<= 1) osum += __shfl_xor(osum, m);
        if (lane == 0) wred[wid][oc] = osum;
    }
    __syncthreads();
    if (tid < OCT)
        atomicAdd(&hsum0[b * 64 + ocBase + tid],
                  wred[0][tid] + wred[1][tid] + wred[2][tid] + wred[3][tid]);
}

// ---------------------------------------------------------------------------
// Pixel shuffle + fused 5x5 skip conv + IMAGE_MEAN. out [8,3,128,128]
// ---------------------------------------------------------------------------
__global__ __launch_bounds__(256) void shuffle_skip(
    const float* __restrict__ body, const float* __restrict__ x,
    const float* __restrict__ skw, const float* __restrict__ skb,
    float* __restrict__ out) {
    __shared__ float w[900];
    __shared__ float bb[12];
    int tid = threadIdx.x;
    for (int i = tid; i < 900; i += 256) w[i] = skw[i];
    if (tid < 12) bb[tid] = skb[tid];
    __syncthreads();
    int idx = blockIdx.x * 256 + tid;
    int ox = idx & 127;
    int oy = (idx >> 7) & 127;
    int v = idx >> 14;
    int c = v % 3;
    int b = v / 3;
    int rx = ox & 1, ry = oy & 1;
    int xx = ox >> 1, yy = oy >> 1;
    int ch = c * 4 + ry * 2 + rx;
    float acc = bb[ch];
    for (int ic = 0; ic < 3; ++ic)
        for (int ky = 0; ky < 5; ++ky) {
            int gy = yy + ky - 2;
            if (gy < 0 || gy >= 64) continue;
            for (int kx = 0; kx < 5; ++kx) {
                int gx = xx + kx - 2;
                if (gx < 0 || gx >= 64) continue;
                acc += w[((ch * 3 + ic) * 5 + ky) * 5 + kx] *
                       (x[((size_t)(b * 3 + ic) * 64 + gy) * 64 + gx] - 0.5f);
            }
        }
    size_t src = (((size_t)b * 12 + ch) * 64 + yy) * 64 + xx;
    out[idx] = body[src] + acc + 0.5f;
}

// ---------------------------------------------------------------------------
extern "C" void kernel_launch(void* const* d_in, const int* in_sizes, int n_in,
                              void* d_out, int out_size, void* d_ws, size_t ws_size,
                              hipStream_t stream) {
    const float* x      = (const float*)d_in[0];
    const float* head_v = (const float*)d_in[1];
    const float* head_g = (const float*)d_in[2];
    const float* head_b = (const float*)d_in[3];
    const float* b1_v   = (const float*)d_in[4];
    const float* b1_g   = (const float*)d_in[5];
    const float* b1_b   = (const float*)d_in[6];
    const float* b1_mw  = (const float*)d_in[7];
    const float* b1_mb  = (const float*)d_in[8];
    const float* b2_v   = (const float*)d_in[9];
    const float* b2_g   = (const float*)d_in[10];
    const float* b2_b   = (const float*)d_in[11];
    const float* b2_mw  = (const float*)d_in[12];
    const float* b2_mb  = (const float*)d_in[13];
    const float* tail_v = (const float*)d_in[14];
    const float* tail_g = (const float*)d_in[15];
    const float* tail_b = (const float*)d_in[16];
    const float* skip_v = (const float*)d_in[17];
    const float* skip_g = (const float*)d_in[18];
    const float* skip_b = (const float*)d_in[19];

    float* ws = (float*)d_ws;
    size_t off = 0;
    auto alloc = [&](size_t n) { float* p = ws + off; off += (n + 3) & ~(size_t)3; return p; };
    float* head_w = alloc(64 * 27);
    float* tail_w = alloc(12 * 576);
    float* skip_w = alloc(12 * 75);
    float* b1_sc  = alloc(2048);
    float* b2_sc  = alloc(512);
    float* h      = alloc((size_t)8 * 64 * 4096);
    float* sums   = alloc(10240);   // hsum[4] @ l*512 ; tsum[4] @ 2048 + l*2048
    float* sbuf   = alloc(64);
    float* body   = alloc((size_t)8 * 12 * 4096);
    unsigned short* wq1  = (unsigned short*)alloc((size_t)8 * 256 * 576 / 2);
    unsigned short* wq2  = (unsigned short*)alloc((size_t)8 * 64 * 2304 / 2);
    unsigned short* wqt  = (unsigned short*)alloc(9216 / 2);
    unsigned short* h_bf = (unsigned short*)alloc((size_t)8 * 66 * 66 * 64 / 2);
    unsigned short* t_bf = (unsigned short*)alloc((size_t)8 * 4 * 66 * 66 * 64 / 2);
    (void)ws_size; (void)in_sizes; (void)n_in; (void)out_size;

    auto hsum = [&](int l) { return sums + l * 512; };
    auto tsum = [&](int l) { return sums + 2048 + l * 2048; };

    zero_all<<<335, 256, 0, stream>>>(h_bf, t_bf, sums);
    wn_all<<<2648, 256, 0, stream>>>(head_v, head_g, head_w, tail_v, tail_g, tail_w,
                                     skip_v, skip_g, skip_w, b1_v, b1_g, b1_sc,
                                     b2_v, b2_g, b2_sc);
    head_conv<<<dim3(4, 4, 8), 256, 0, stream>>>(x, head_w, head_b, h, h_bf, hsum(0));
    tail_repack<<<36, 256, 0, stream>>>(tail_w, wqt);

    for (int l = 0; l < 4; ++l) {
        // dyn conv 1: 64 -> 256, relu. 4 waves WM=1 WN=4, NR=4, 3 blocks/CU.
        combine_v2<64, 4, 2><<<dim3(64, 8), 256, 0, stream>>>(
            b1_v + (size_t)l * 512 * 576, b1_sc + (size_t)l * 512, hsum(l),
            b1_mw + (size_t)l * 8 * 64, b1_mb + l * 8, sbuf, wq1, 64, 256);
        conv_mfma<64, 256, 64, 1, 4, 4, true, false, false, true, 256, true>
            <<<dim3(16, 4, 8), 256, 0, stream>>>(h_bf, wq1, b1_b + (size_t)l * 512, sbuf, 6,
                                                 nullptr, nullptr, t_bf, tsum(l), 147456);
        // dyn conv 2: 256 -> 64, +residual h. 8 waves WM=2 WN=4, NR=2.
        combine_v2<256, 2, 1><<<dim3(32, 8), 256, 0, stream>>>(
            b2_v + (size_t)l * 128 * 2304, b2_sc + (size_t)l * 128, tsum(l),
            b2_mw + (size_t)l * 8 * 256, b2_mb + l * 8, sbuf, wq2, 16, 64);
        conv_mfma<256, 64, 64, 2, 4, 2, false, true, true, true, 64, true>
            <<<dim3(32, 1, 8), 512, 0, stream>>>(t_bf, wq2, b2_b + (size_t)l * 128, sbuf, 4,
                                                 h, h, h_bf, (l < 3) ? hsum(l + 1) : nullptr,
                                                 147456);
    }

    // tail: 64 -> 12 via MFMA (padded to 16)
    conv_mfma<64, 16, 16, 1, 4, 4, false, false, true, false, 12, false>
        <<<dim3(16, 1, 8), 256, 0, stream>>>(h_bf, wqt, tail_b, nullptr, 0,
                                             nullptr, body, nullptr, nullptr, 0);
    // pixel shuffle + fused skip conv
    shuffle_skip<<<1536, 256, 0, stream>>>(body, x, skip_w, skip_b, (float*)d_out);
}

// Round 7
// 336.779 us; speedup vs baseline: 1.0855x; 1.0583x over previous
//
#include <hip/hip_runtime.h>

typedef __attribute__((ext_vector_type(8))) short bf16x8;
typedef __attribute__((ext_vector_type(4))) float f32x4;
typedef __attribute__((ext_vector_type(8))) unsigned short u16x8;

__device__ __forceinline__ unsigned short bf16u(float x) {
    unsigned int u = __builtin_bit_cast(unsigned int, x);
    unsigned int r = (u + 0x7fffu + ((u >> 16) & 1u)) >> 16;
    return (unsigned short)r;
}
__device__ __forceinline__ float bf2f(unsigned short u) {
    return __builtin_bit_cast(float, (unsigned int)u << 16);
}
__device__ __forceinline__ void gll16(const void* g, void* l) {
    __builtin_amdgcn_global_load_lds((const __attribute__((address_space(1))) void*)g,
                                     (__attribute__((address_space(3))) void*)l, 16, 0, 0);
}

// ---------------------------------------------------------------------------
// Zero: h_bf borders (2 slabs), t_bf borders (8 slabs), sum buffers.
// Layouts: [b][cb][66][66][32] bf16. grid 335x256.
// ---------------------------------------------------------------------------
__global__ __launch_bounds__(256) void zero_all(unsigned short* __restrict__ hbf,
                                                unsigned short* __restrict__ tbf,
                                                float* __restrict__ sums) {
    int i = blockIdx.x * 256 + threadIdx.x;
    u16x8 z8 = {0, 0, 0, 0, 0, 0, 0, 0};
    if (i < 16640) {          // h_bf: 8b*2cb*260*4chunks
        int chv = i & 3, pb = i >> 2, pos = pb % 260, bc = pb / 260;
        int y, x;
        if (pos < 66) { y = 0; x = pos; }
        else if (pos < 132) { y = 65; x = pos - 66; }
        else if (pos < 196) { y = pos - 131; x = 0; }
        else { y = pos - 195; x = 65; }
        *(u16x8*)&hbf[((size_t)bc * 4356 + y * 66 + x) * 32 + chv * 8] = z8;
    } else if (i < 83200) {   // t_bf: 8b*8cb*260*4chunks
        int j = i - 16640;
        int chv = j & 3, pb = j >> 2, pos = pb % 260, bc = pb / 260;
        int y, x;
        if (pos < 66) { y = 0; x = pos; }
        else if (pos < 132) { y = 65; x = pos - 66; }
        else if (pos < 196) { y = pos - 131; x = 0; }
        else { y = pos - 195; x = 65; }
        *(u16x8*)&tbf[((size_t)bc * 4356 + y * 66 + x) * 32 + chv * 8] = z8;
    } else {
        int k = i - 83200;    // < 2560
        f32x4 z4 = {0.f, 0.f, 0.f, 0.f};
        ((f32x4*)sums)[k] = z4;
    }
}

// ---------------------------------------------------------------------------
// All weight norms in one launch.
// ---------------------------------------------------------------------------
__global__ __launch_bounds__(256) void wn_all(
    const float* __restrict__ hv, const float* __restrict__ hg, float* __restrict__ hw,
    const float* __restrict__ tv, const float* __restrict__ tg, float* __restrict__ tw,
    const float* __restrict__ kv, const float* __restrict__ kg, float* __restrict__ kw,
    const float* __restrict__ b1v, const float* __restrict__ b1g, float* __restrict__ b1s,
    const float* __restrict__ b2v, const float* __restrict__ b2g, float* __restrict__ b2s) {
    int blk = blockIdx.x;
    const float *v, *g;
    float *outw = nullptr, *outs = nullptr;
    int len, row;
    if (blk < 64)        { v = hv;  g = hg;  outw = hw;  len = 27;   row = blk; }
    else if (blk < 76)   { v = tv;  g = tg;  outw = tw;  len = 576;  row = blk - 64; }
    else if (blk < 88)   { v = kv;  g = kg;  outw = kw;  len = 75;   row = blk - 76; }
    else if (blk < 2136) { v = b1v; g = b1g; outs = b1s; len = 576;  row = blk - 88; }
    else                 { v = b2v; g = b2g; outs = b2s; len = 2304; row = blk - 2136; }

    __shared__ float red[4];
    __shared__ float s_sc;
    const float* vr = v + (size_t)row * len;
    float ss = 0.f;
    for (int i = threadIdx.x; i < len; i += 256) { float a = vr[i]; ss += a * a; }
    for (int o = 32; o > 0; o >>= 1) ss += __shfl_down(ss, o);
    if ((threadIdx.x & 63) == 0) red[threadIdx.x >> 6] = ss;
    __syncthreads();
    if (threadIdx.x == 0) s_sc = g[row] / sqrtf(red[0] + red[1] + red[2] + red[3]);
    __syncthreads();
    float sc = s_sc;
    if (outs) {
        if (threadIdx.x == 0) outs[row] = sc;
    } else {
        float* orow = outw + (size_t)row * len;
        for (int i = threadIdx.x; i < len; i += 256) orow[i] = vr[i] * sc;
    }
}

// ---------------------------------------------------------------------------
// Coalesced per-sample weight combine + in-block routing softmax.
// wq layout [b][ot][kc][t][kg][mo(2^LGMO)][kj(8)].
// ---------------------------------------------------------------------------
template <int IC, int GOC, int LGG, int LGMO>
__global__ __launch_bounds__(256) void combine_v2(
    const float* __restrict__ v, const float* __restrict__ scale,
    const float* __restrict__ msum, const float* __restrict__ mw,
    const float* __restrict__ mb, float* __restrict__ s_out,
    unsigned short* __restrict__ wq, int D, int OC) {
    constexpr int ROWF = IC * 9;
    constexpr int KCh = IC / 32;
    constexpr int TOTC = GOC * KCh * 9 * 4;
    __shared__ float lv[2 * GOC * ROWF];
    __shared__ float lg[8], sv8[8];
    int tid = threadIdx.x;
    int b = blockIdx.y, ocg = blockIdx.x * GOC;
    {
        int j = tid >> 5, l32 = tid & 31;
        float part = 0.f;
        for (int i = l32; i < IC; i += 32) part += msum[b * IC + i] * mw[j * IC + i];
        for (int m = 16; m > 0; m >>= 1) part += __shfl_xor(part, m);
        if (l32 == 0) lg[j] = part * (1.f / 4096.f) + mb[j];
    }
    for (int i = tid; i < 2 * GOC * ROWF; i += 256) {
        int r = i / ROWF, jj = i - r * ROWF;
        int oc_r = (r / GOC) * OC + ocg + (r % GOC);
        lv[i] = v[(size_t)oc_r * ROWF + jj] * scale[oc_r];
    }
    __syncthreads();
    if (tid < 8) {
        int g = tid >> 2, c = tid & 3;
        float l0 = lg[c], l1 = lg[4 + c];
        float m = fmaxf(l0, l1);
        float e0 = __expf(l0 - m), e1 = __expf(l1 - m);
        float val = ((g == 0) ? e0 : e1) / (e0 + e1);
        sv8[tid] = val;
        if (blockIdx.x == 0) s_out[b * 8 + tid] = val;
    }
    __syncthreads();
    for (int ci = tid; ci < TOTC; ci += 256) {
        int ml = ci & (GOC - 1);
        int c = ci >> LGG;
        int kg = c & 3, c2 = c >> 2;
        int t = c2 % 9, kc = c2 / 9;
        int oc = ocg + ml;
        int cd = oc / D;
        float s0 = sv8[cd], s1 = sv8[4 + cd];
        const float* p0 = &lv[(size_t)ml * ROWF];
        const float* p1 = &lv[(size_t)(GOC + ml) * ROWF];
        u16x8 pk;
#pragma unroll
        for (int kj = 0; kj < 8; ++kj) {
            int ic9 = (kc * 32 + kg * 8 + kj) * 9 + t;
            pk[kj] = bf16u(s0 * p0[ic9] + s1 * p1[ic9]);
        }
        size_t w_off = ((((size_t)(b * (OC >> LGMO) + (oc >> LGMO)) * KCh + kc) * 9 + t) * 4 + kg)
                           * ((1 << LGMO) * 8) + (size_t)(oc & ((1 << LGMO) - 1)) * 8;
        *(u16x8*)&wq[w_off] = pk;
    }
}

// Static tail weight repack: [kc=2][t][kg][mo=16][kj], zeros for mo>=12
__global__ void tail_repack(const float* __restrict__ tw, unsigned short* __restrict__ wq) {
    int idx = blockIdx.x * 256 + threadIdx.x;  // 9216
    int kj = idx & 7;
    int tmp = idx >> 3;
    int mo = tmp % 16; tmp /= 16;
    int kg = tmp & 3; tmp >>= 2;
    int t = tmp % 9; tmp /= 9;
    int kc = tmp;
    int ic = kc * 32 + kg * 8 + kj;
    float val = (mo < 12) ? tw[((size_t)mo * 64 + ic) * 9 + t] : 0.f;
    wq[idx] = bf16u(val);
}

// ---------------------------------------------------------------------------
// MFMA implicit-GEMM 3x3 conv. Input [b][IC/32][66][66][32] bf16 slabs.
// S double-buffered + prefetch; A-frags from global to VGPR (1-tap prefetch).
// WBF epilogue: shfl-exchange -> dense 16B stores; optional in-place bf16
// residual (RES) and post-residual msum. WF32 path kept for tail.
//   grid = (strips, b, ot); block = WM*WN*64 threads.
// ---------------------------------------------------------------------------
template <int IC, int OC, int MT, int WM, int WN, int NR,
          bool RELU, bool RES, bool WF32, bool WBF, int OCR, bool DYNB, int MINW>
__global__ __launch_bounds__(WM * WN * 64, MINW)
void conv_mfma(
    const unsigned short* __restrict__ in_bf,
    const unsigned short* __restrict__ wq,
    const float* __restrict__ bias_raw, const float* __restrict__ s8, int lgD,
    float* __restrict__ out,
    unsigned short* __restrict__ out_bf, float* __restrict__ msum, long wstride) {
    constexpr int THREADS = WM * WN * 64;
    constexpr int KCH = IC / 32;
    constexpr int NRH = NR + 2;
    constexpr int NT = NR * 64;
    constexpr int NF = (NT / 16) / WN;
    constexpr int MW = MT / (16 * WM);
    constexpr int WELEM = 9 * 32 * MT;
    constexpr int SELEM = NRH * 66 * 32;
    constexpr int SCH = SELEM / 8;
    constexpr int OCB = OCR / 32;

    __shared__ __align__(16) unsigned short S[2][SELEM];
    __shared__ float MRED[WN][MT];

    const int b = blockIdx.y, ot = blockIdx.z;
    const int y0 = blockIdx.x * NR;
    const int tid = threadIdx.x;
    const int lane = tid & 63;
    const int wid = tid >> 6;
    const int wm = wid / WN, wn = wid % WN;
    const int l15 = lane & 15, lk = lane >> 4;
    const int wmo = wm * (MT / WM);
    const int wno = wn * (NT / WN);

    f32x4 acc[MW][NF];
#pragma unroll
    for (int mf = 0; mf < MW; ++mf)
#pragma unroll
        for (int nf = 0; nf < NF; ++nf)
#pragma unroll
            for (int q = 0; q < 4; ++q) acc[mf][nf][q] = 0.f;

    const unsigned short* inb = in_bf + (size_t)b * KCH * (4356 * 32);
    const unsigned short* wqb = wq + (size_t)b * wstride + (size_t)ot * (KCH * WELEM);
    const unsigned short* wqa = wqb + (size_t)lk * (MT * 8) + (size_t)(wmo + l15) * 8;

    auto STAGE_S = [&](int kc, int buf) {
        const unsigned short* sb = inb + (size_t)kc * (4356 * 32);
        for (int i = tid; i < SCH; i += THREADS) {
            int Lz = i ^ ((i >> 3) & 7);
            int lk2 = Lz & 3, cr = Lz >> 2;
            int col = cr % 66, row = cr / 66;
            gll16(sb + ((size_t)(y0 + row) * 66 + col) * 32 + lk2 * 8,
                  (char*)S[buf] + i * 16);
        }
    };

    STAGE_S(0, 0);
    __syncthreads();
    for (int kc = 0; kc < KCH; ++kc) {
        if (kc + 1 < KCH) STAGE_S(kc + 1, (kc + 1) & 1);
        const unsigned short* Sb = S[kc & 1];
        const unsigned short* wk = wqa + (size_t)kc * WELEM;
        bf16x8 aN[MW];
#pragma unroll
        for (int mf = 0; mf < MW; ++mf)
            aN[mf] = *(const bf16x8*)(wk + mf * (16 * 8));
#pragma unroll
        for (int t = 0; t < 9; ++t) {
            const int dy = t / 3, dx = t % 3;
            bf16x8 aC[MW];
#pragma unroll
            for (int mf = 0; mf < MW; ++mf) aC[mf] = aN[mf];
            if (t < 8) {
#pragma unroll
                for (int mf = 0; mf < MW; ++mf)
                    aN[mf] = *(const bf16x8*)(wk + (t + 1) * (4 * MT * 8) + mf * (16 * 8));
            }
#pragma unroll
            for (int nf = 0; nf < NF; ++nf) {
                int n = wno + nf * 16 + l15;
                int r = n >> 6, c = n & 63;
                int L = ((r + dy) * 66 + (c + dx)) * 4 + lk;
                int P = L ^ ((L >> 3) & 7);
                bf16x8 bv = *(const bf16x8*)((const char*)Sb + P * 16);
#pragma unroll
                for (int mf = 0; mf < MW; ++mf)
                    acc[mf][nf] = __builtin_amdgcn_mfma_f32_16x16x32_bf16(aC[mf], bv, acc[mf][nf], 0, 0, 0);
            }
        }
        __syncthreads();
    }

    if constexpr (WBF) {
        static_assert(NF == 2, "shuffle epilogue needs NF==2");
        const int mynf = lk & 1;
        const int ch = lk >> 1;
        const bool evenlk = ((lk & 1) == 0);
#pragma unroll
        for (int mf = 0; mf < MW; ++mf) {
            int ocb = ot * MT + wmo + mf * 16 + lk * 4;
            float bvv[4];
#pragma unroll
            for (int q = 0; q < 4; ++q) {
                int oc = ocb + q;
                if (DYNB) {
                    int cc = oc >> lgD;
                    bvv[q] = s8[b * 8 + cc] * bias_raw[oc] + s8[b * 8 + 4 + cc] * bias_raw[OCR + oc];
                } else {
                    bvv[q] = bias_raw[oc];
                }
            }
            float r[2][4], pr[2][4];
#pragma unroll
            for (int nf = 0; nf < 2; ++nf)
#pragma unroll
                for (int q = 0; q < 4; ++q) {
                    float v = acc[mf][nf][q] + bvv[q];
                    if (RELU) v = fmaxf(v, 0.f);
                    r[nf][q] = v;
                }
#pragma unroll
            for (int nf = 0; nf < 2; ++nf)
#pragma unroll
                for (int q = 0; q < 4; ++q) pr[nf][q] = __shfl_xor(r[nf][q], 16);
            float v8[8];
#pragma unroll
            for (int q = 0; q < 4; ++q) {
                float a = r[mynf][q], p = pr[mynf][q];
                v8[q] = evenlk ? a : p;
                v8[4 + q] = evenlk ? p : a;
            }
            int n = wno + mynf * 16 + l15;
            int y = y0 + (n >> 6), x = n & 63;
            int occ = ot * MT + wmo + mf * 16 + ch * 8;
            size_t addr = ((((size_t)b * OCB + (occ >> 5)) * 66 + (y + 1)) * 66 + (x + 1)) * 32
                          + (occ & 31);
            if (RES) {
                u16x8 rv = *(const u16x8*)&out_bf[addr];
#pragma unroll
                for (int j = 0; j < 8; ++j) v8[j] += bf2f(rv[j]);
            }
            u16x8 pk;
#pragma unroll
            for (int j = 0; j < 8; ++j) pk[j] = bf16u(v8[j]);
            *(u16x8*)&out_bf[addr] = pk;
            if (msum) {
#pragma unroll
                for (int j = 0; j < 8; ++j) {
                    float t = v8[j];
                    t += __shfl_xor(t, 1);
                    t += __shfl_xor(t, 2);
                    t += __shfl_xor(t, 4);
                    t += __shfl_xor(t, 8);
                    t += __shfl_xor(t, 16);
                    v8[j] = t;
                }
                if ((lane & 31) == 0) {
#pragma unroll
                    for (int j = 0; j < 8; ++j)
                        MRED[wn][wmo + mf * 16 + ch * 8 + j] = v8[j];
                }
            }
        }
        if (msum) {
            __syncthreads();
            if (tid < MT) {
                float tot = 0.f;
#pragma unroll
                for (int w2 = 0; w2 < WN; ++w2) tot += MRED[w2][tid];
                atomicAdd(&msum[b * OCR + ot * MT + tid], tot);
            }
        }
    }
    if constexpr (WF32) {
#pragma unroll
        for (int mf = 0; mf < MW; ++mf) {
            int ocb = ot * MT + wmo + mf * 16 + lk * 4;
#pragma unroll
            for (int nf = 0; nf < NF; ++nf) {
                int n = wno + nf * 16 + l15;
                int y = y0 + (n >> 6), x = n & 63;
#pragma unroll
                for (int q = 0; q < 4; ++q) {
                    int oc = ocb + q;
                    if (oc < OCR) {
                        float v = acc[mf][nf][q] + bias_raw[oc];
                        out[(((size_t)b * OCR + oc) * 64 + y) * 64 + x] = v;
                    }
                }
            }
        }
    }
}

// ---------------------------------------------------------------------------
// Head conv 3->64 direct fp32; writes h_bf (slab-32 layout) + hsum0.
// ---------------------------------------------------------------------------
__global__ __launch_bounds__(256) void head_conv(
    const float* __restrict__ in, const float* __restrict__ w,
    const float* __restrict__ bias,
    unsigned short* __restrict__ out_bf, float* __restrict__ hsum0) {
    constexpr int OCT = 16, IC = 3;
    __shared__ float s_in[34 * 34];
    __shared__ float s_w[OCT * 9];
    __shared__ float wred[4][OCT];
    int b = blockIdx.z;
    int ocBase = blockIdx.y * OCT;
    int ty0 = (blockIdx.x >> 1) * 32;
    int tx0 = (blockIdx.x & 1) * 32;
    int tid = threadIdx.x;
    int lane = tid & 63, wid = tid >> 6;
    int tx = tid & 15, ty = tid >> 4;

    float acc[OCT][4];
#pragma unroll
    for (int oc = 0; oc < OCT; ++oc)
#pragma unroll
        for (int p = 0; p < 4; ++p) acc[oc][p] = 0.f;

    const float* inb = in + (size_t)b * IC * 4096;
    for (int ic = 0; ic < IC; ++ic) {
        const float* src = inb + (size_t)ic * 4096;
        for (int i = tid; i < 34 * 34; i += 256) {
            int r = i / 34, cc = i % 34;
            int gy = ty0 + r - 1, gx = tx0 + cc - 1;
            float val = 0.f;
            if (gy >= 0 && gy < 64 && gx >= 0 && gx < 64) val = src[gy * 64 + gx] - 0.5f;
            s_in[i] = val;
        }
        for (int i = tid; i < OCT * 9; i += 256) {
            int oc = i / 9, t = i % 9;
            s_w[i] = w[((size_t)(ocBase + oc) * IC + ic) * 9 + t];
        }
        __syncthreads();
        float v[4][4];
#pragma unroll
        for (int r = 0; r < 4; ++r)
#pragma unroll
            for (int cc = 0; cc < 4; ++cc) v[r][cc] = s_in[(2 * ty + r) * 34 + (2 * tx + cc)];
#pragma unroll
        for (int oc = 0; oc < OCT; ++oc) {
#pragma unroll
            for (int ky = 0; ky < 3; ++ky)
#pragma unroll
                for (int kx = 0; kx < 3; ++kx) {
                    float wv = s_w[oc * 9 + ky * 3 + kx];
                    acc[oc][0] += wv * v[ky][kx];
                    acc[oc][1] += wv * v[ky][kx + 1];
                    acc[oc][2] += wv * v[ky + 1][kx];
                    acc[oc][3] += wv * v[ky + 1][kx + 1];
                }
        }
        __syncthreads();
    }
    int py = ty0 + 2 * ty, px = tx0 + 2 * tx;
#pragma unroll
    for (int oc = 0; oc < OCT; ++oc) {
        int og = ocBase + oc;
        float bv = bias[og];
        float osum = 0.f;
#pragma unroll
        for (int p = 0; p < 4; ++p) {
            int dy = p >> 1, dx = p & 1;
            float val = acc[oc][p] + bv;
            osum += val;
            out_bf[((size_t)(b * 2 + (og >> 5)) * 4356 + (py + dy + 1) * 66 + (px + dx + 1)) * 32
                   + (og & 31)] = bf16u(val);
        }
        for (int m = 1; m < 64; m <<= 1) osum += __shfl_xor(osum, m);
        if (lane == 0) wred[wid][oc] = osum;
    }
    __syncthreads();
    if (tid < OCT)
        atomicAdd(&hsum0[b * 64 + ocBase + tid],
                  wred[0][tid] + wred[1][tid] + wred[2][tid] + wred[3][tid]);
}

// ---------------------------------------------------------------------------
// Pixel shuffle + fused 5x5 skip conv + IMAGE_MEAN. out [8,3,128,128]
// ---------------------------------------------------------------------------
__global__ __launch_bounds__(256) void shuffle_skip(
    const float* __restrict__ body, const float* __restrict__ x,
    const float* __restrict__ skw, const float* __restrict__ skb,
    float* __restrict__ out) {
    __shared__ float w[900];
    __shared__ float bb[12];
    int tid = threadIdx.x;
    for (int i = tid; i < 900; i += 256) w[i] = skw[i];
    if (tid < 12) bb[tid] = skb[tid];
    __syncthreads();
    int idx = blockIdx.x * 256 + tid;
    int ox = idx & 127;
    int oy = (idx >> 7) & 127;
    int v = idx >> 14;
    int c = v % 3;
    int b = v / 3;
    int rx = ox & 1, ry = oy & 1;
    int xx = ox >> 1, yy = oy >> 1;
    int ch = c * 4 + ry * 2 + rx;
    float acc = bb[ch];
    for (int ic = 0; ic < 3; ++ic)
        for (int ky = 0; ky < 5; ++ky) {
            int gy = yy + ky - 2;
            if (gy < 0 || gy >= 64) continue;
            for (int kx = 0; kx < 5; ++kx) {
                int gx = xx + kx - 2;
                if (gx < 0 || gx >= 64) continue;
                acc += w[((ch * 3 + ic) * 5 + ky) * 5 + kx] *
                       (x[((size_t)(b * 3 + ic) * 64 + gy) * 64 + gx] - 0.5f);
            }
        }
    size_t src = (((size_t)b * 12 + ch) * 64 + yy) * 64 + xx;
    out[idx] = body[src] + acc + 0.5f;
}

// ---------------------------------------------------------------------------
extern "C" void kernel_launch(void* const* d_in, const int* in_sizes, int n_in,
                              void* d_out, int out_size, void* d_ws, size_t ws_size,
                              hipStream_t stream) {
    const float* x      = (const float*)d_in[0];
    const float* head_v = (const float*)d_in[1];
    const float* head_g = (const float*)d_in[2];
    const float* head_b = (const float*)d_in[3];
    const float* b1_v   = (const float*)d_in[4];
    const float* b1_g   = (const float*)d_in[5];
    const float* b1_b   = (const float*)d_in[6];
    const float* b1_mw  = (const float*)d_in[7];
    const float* b1_mb  = (const float*)d_in[8];
    const float* b2_v   = (const float*)d_in[9];
    const float* b2_g   = (const float*)d_in[10];
    const float* b2_b   = (const float*)d_in[11];
    const float* b2_mw  = (const float*)d_in[12];
    const float* b2_mb  = (const float*)d_in[13];
    const float* tail_v = (const float*)d_in[14];
    const float* tail_g = (const float*)d_in[15];
    const float* tail_b = (const float*)d_in[16];
    const float* skip_v = (const float*)d_in[17];
    const float* skip_g = (const float*)d_in[18];
    const float* skip_b = (const float*)d_in[19];

    float* ws = (float*)d_ws;
    size_t off = 0;
    auto alloc = [&](size_t n) { float* p = ws + off; off += (n + 3) & ~(size_t)3; return p; };
    float* head_w = alloc(64 * 27);
    float* tail_w = alloc(12 * 576);
    float* skip_w = alloc(12 * 75);
    float* b1_sc  = alloc(2048);
    float* b2_sc  = alloc(512);
    float* sums   = alloc(10240);   // hsum[4] @ l*512 ; tsum[4] @ 2048 + l*2048
    float* sbuf   = alloc(64);
    float* body   = alloc((size_t)8 * 12 * 4096);
    unsigned short* wq1  = (unsigned short*)alloc((size_t)8 * 256 * 576 / 2);
    unsigned short* wq2  = (unsigned short*)alloc((size_t)8 * 64 * 2304 / 2);
    unsigned short* wqt  = (unsigned short*)alloc(9216 / 2);
    unsigned short* h_bf = (unsigned short*)alloc((size_t)8 * 2 * 4356 * 32 / 2);
    unsigned short* t_bf = (unsigned short*)alloc((size_t)8 * 8 * 4356 * 32 / 2);
    (void)ws_size; (void)in_sizes; (void)n_in; (void)out_size;

    auto hsum = [&](int l) { return sums + l * 512; };
    auto tsum = [&](int l) { return sums + 2048 + l * 2048; };

    zero_all<<<335, 256, 0, stream>>>(h_bf, t_bf, sums);
    wn_all<<<2648, 256, 0, stream>>>(head_v, head_g, head_w, tail_v, tail_g, tail_w,
                                     skip_v, skip_g, skip_w, b1_v, b1_g, b1_sc,
                                     b2_v, b2_g, b2_sc);
    head_conv<<<dim3(4, 4, 8), 256, 0, stream>>>(x, head_w, head_b, h_bf, hsum(0));
    tail_repack<<<36, 256, 0, stream>>>(tail_w, wqt);

    for (int l = 0; l < 4; ++l) {
        // dyn conv 1: 64 -> 256, relu. MT=32, NR=2, 2048 blocks, 4 blk/CU.
        combine_v2<64, 4, 2, 5><<<dim3(64, 8), 256, 0, stream>>>(
            b1_v + (size_t)l * 512 * 576, b1_sc + (size_t)l * 512, hsum(l),
            b1_mw + (size_t)l * 8 * 64, b1_mb + l * 8, sbuf, wq1, 64, 256);
        conv_mfma<64, 256, 32, 1, 4, 2, true, false, false, true, 256, true, 4>
            <<<dim3(32, 8, 8), 256, 0, stream>>>(h_bf, wq1, b1_b + (size_t)l * 512, sbuf, 6,
                                                 nullptr, t_bf, tsum(l), 147456);
        // dyn conv 2: 256 -> 64, bf16 in-place residual into h_bf. 8 waves.
        combine_v2<256, 2, 1, 6><<<dim3(32, 8), 256, 0, stream>>>(
            b2_v + (size_t)l * 128 * 2304, b2_sc + (size_t)l * 128, tsum(l),
            b2_mw + (size_t)l * 8 * 256, b2_mb + l * 8, sbuf, wq2, 16, 64);
        conv_mfma<256, 64, 64, 2, 4, 2, false, true, false, true, 64, true, 2>
            <<<dim3(32, 8, 1), 512, 0, stream>>>(t_bf, wq2, b2_b + (size_t)l * 128, sbuf, 4,
                                                 nullptr, h_bf, (l < 3) ? hsum(l + 1) : nullptr,
                                                 147456);
    }

    // tail: 64 -> 12 via MFMA (padded to 16), fp32 body out
    conv_mfma<64, 16, 16, 1, 4, 4, false, false, true, false, 12, false, 2>
        <<<dim3(16, 8, 1), 256, 0, stream>>>(h_bf, wqt, tail_b, nullptr, 0,
                                             body, nullptr, nullptr, 0);
    // pixel shuffle + fused skip conv
    shuffle_skip<<<1536, 256, 0, stream>>>(body, x, skip_w, skip_b, (float*)d_out);
}